// Round 1
// baseline (515.489 us; speedup 1.0000x reference)
//
#include <hip/hip_runtime.h>
#include <math.h>

#define VOCAB 100000
#define EMBED 512
#define WINDOW 10
#define PATH 17
#define EPS 1e-9f

// Single-block kernel; the whole problem is ~55 KB of gathered reads,
// ~14K MACs, one scalar out. Structured for ONE global-latency round:
// node-row loads (independent of h) are issued before the barrier.
// All gathers are float4 (global_load_dwordx4): node rows 24->6 loads/thread,
// h-phase 5120->1280 total loads. LDS h reads are ds_read_b128 (16B/lane
// consecutive = 2 lanes/bank = conflict-free per m136).
__global__ __launch_bounds__(512)
void cbow_hs_kernel(const int* __restrict__ context_idx,
                    const int* __restrict__ path_indices,
                    const int* __restrict__ code_bits,
                    const float* __restrict__ ctx_emb,
                    const float* __restrict__ node_emb,
                    float* __restrict__ out) {
    __shared__ float h_s[EMBED];
    __shared__ float loss_s;

    const int tid  = threadIdx.x;
    const int wave = tid >> 6;   // 0..7
    const int lane = tid & 63;

    if (tid == 0) loss_s = 0.0f;

    // ---- Prefetch this wave's node rows into registers (independent of h).
    // Wave w handles paths w, w+8, w+16 (only wave 0 has a third path).
    const int p0 = wave;
    const int p1 = wave + 8;
    const int p2 = wave + 16;
    const bool has1 = p1 < PATH;
    const bool has2 = p2 < PATH;
    // clamp OOB path slots to a valid index (result predicated away later)
    const int r0 = path_indices[p0];
    const int r1 = path_indices[has1 ? p1 : 0];
    const int r2 = path_indices[has2 ? p2 : 0];

    // Row = 512 floats = 128 float4. Lane covers float4 indices {lane, lane+64},
    // i.e. row elements 4*lane..4*lane+3 and 4*lane+256..4*lane+259.
    float4 n0v[2], n1v[2], n2v[2];
    {
        const float4* a0 = (const float4*)(node_emb + (size_t)r0 * EMBED);
        const float4* a1 = (const float4*)(node_emb + (size_t)r1 * EMBED);
        const float4* a2 = (const float4*)(node_emb + (size_t)r2 * EMBED);
        #pragma unroll
        for (int j = 0; j < 2; ++j) n0v[j] = a0[lane + 64 * j];
        #pragma unroll
        for (int j = 0; j < 2; ++j) n1v[j] = a1[lane + 64 * j];
        #pragma unroll
        for (int j = 0; j < 2; ++j) n2v[j] = a2[lane + 64 * j];
    }

    // ---- Phase 1: h = mean over window. Waves 0-1 (128 threads) each own
    // 4 consecutive elements via float4; loads are coalesced dwordx4 and
    // issue behind the node loads (one latency round covers both). The
    // other 6 waves proceed straight to the barrier with node data in flight.
    if (tid < 128) {
        float4 acc = make_float4(0.0f, 0.0f, 0.0f, 0.0f);
        #pragma unroll
        for (int w = 0; w < WINDOW; ++w) {
            const int row = context_idx[w];   // uniform -> s_load
            const float4 v = *(const float4*)(ctx_emb + (size_t)row * EMBED + 4 * tid);
            acc.x += v.x; acc.y += v.y; acc.z += v.z; acc.w += v.w;
        }
        const float inv = 1.0f / WINDOW;
        acc.x *= inv; acc.y *= inv; acc.z *= inv; acc.w *= inv;
        *(float4*)(&h_s[4 * tid]) = acc;
    }
    __syncthreads();

    // ---- Phase 2: three dot products per wave from registers + LDS h.
    float s0 = 0.0f, s1 = 0.0f, s2 = 0.0f;
    #pragma unroll
    for (int j = 0; j < 2; ++j) {
        const float4 h = *(const float4*)(&h_s[4 * (lane + 64 * j)]); // ds_read_b128
        s0 += n0v[j].x * h.x + n0v[j].y * h.y + n0v[j].z * h.z + n0v[j].w * h.w;
        s1 += n1v[j].x * h.x + n1v[j].y * h.y + n1v[j].z * h.z + n1v[j].w * h.w;
        s2 += n2v[j].x * h.x + n2v[j].y * h.y + n2v[j].z * h.z + n2v[j].w * h.w;
    }
    // one butterfly for all three sums
    #pragma unroll
    for (int off = 32; off >= 1; off >>= 1) {
        s0 += __shfl_xor(s0, off, 64);
        s1 += __shfl_xor(s1, off, 64);
        s2 += __shfl_xor(s2, off, 64);
    }

    if (lane == 0) {
        float local = 0.0f;
        {
            const float score = 1.0f / (1.0f + expf(-s0));
            local += (code_bits[p0] == 1) ? -logf(score + EPS)
                                          : -logf(1.0f - score + EPS);
        }
        if (has1) {
            const float score = 1.0f / (1.0f + expf(-s1));
            local += (code_bits[p1] == 1) ? -logf(score + EPS)
                                          : -logf(1.0f - score + EPS);
        }
        if (has2) {
            const float score = 1.0f / (1.0f + expf(-s2));
            local += (code_bits[p2] == 1) ? -logf(score + EPS)
                                          : -logf(1.0f - score + EPS);
        }
        atomicAdd(&loss_s, local);
    }
    __syncthreads();

    if (tid == 0) out[0] = loss_s;
}

extern "C" void kernel_launch(void* const* d_in, const int* in_sizes, int n_in,
                              void* d_out, int out_size, void* d_ws, size_t ws_size,
                              hipStream_t stream) {
    const int*   context_idx  = (const int*)d_in[0];
    const int*   path_indices = (const int*)d_in[1];
    const int*   code_bits    = (const int*)d_in[2];
    const float* ctx_emb      = (const float*)d_in[3];
    const float* node_emb     = (const float*)d_in[4];
    float*       out          = (float*)d_out;

    cbow_hs_kernel<<<1, 512, 0, stream>>>(context_idx, path_indices, code_bits,
                                          ctx_emb, node_emb, out);
}